// Round 5
// baseline (1202.580 us; speedup 1.0000x reference)
//
#include <hip/hip_runtime.h>
#include <hip/hip_fp16.h>

#define B_  32
#define L_  2048
#define U_  512
#define H_  8
#define HD_ 64

typedef __attribute__((ext_vector_type(8))) _Float16 half8;
typedef __attribute__((ext_vector_type(4))) float f32x4;

template <bool V> struct BoolC { static constexpr bool value = V; };

// monotonic float->uint map for atomic max (works for negatives)
__device__ __forceinline__ unsigned fmap(float x) {
    unsigned u = __float_as_uint(x);
    return (u & 0x80000000u) ? ~u : (u | 0x80000000u);
}
__device__ __forceinline__ float funmap(unsigned m) {
    unsigned bits = (m & 0x80000000u) ? (m ^ 0x80000000u) : ~m;
    return __uint_as_float(bits);
}

// ---------------------------------------------------------------------------
// Kernel 0: t (B,L,U) fp32 -> fp16 (RTZ, hoisted from the GEMM inner loop).
// ---------------------------------------------------------------------------
__global__ void __launch_bounds__(256) t_cvt(const float* __restrict__ t,
                                             __half* __restrict__ t16) {
    const size_t id = (size_t)blockIdx.x * 256 + threadIdx.x;  // x8 floats
    const float4 a = *(const float4*)(t + id * 8);
    const float4 b = *(const float4*)(t + id * 8 + 4);
    auto p0 = __builtin_amdgcn_cvt_pkrtz(a.x, a.y);
    auto p1 = __builtin_amdgcn_cvt_pkrtz(a.z, a.w);
    auto p2 = __builtin_amdgcn_cvt_pkrtz(b.x, b.y);
    auto p3 = __builtin_amdgcn_cvt_pkrtz(b.z, b.w);
    half8 hv;
    hv[0] = p0[0]; hv[1] = p0[1]; hv[2] = p1[0]; hv[3] = p1[1];
    hv[4] = p2[0]; hv[5] = p2[1]; hv[6] = p3[0]; hv[7] = p3[1];
    *(half8*)(t16 + id * 8) = hv;
}

// ---------------------------------------------------------------------------
// Kernel 1a: repack [Wq;Wk;Wv] (O,I,3) fp32 -> fp16 in DIRECT A-FRAGMENT order:
// Wrp2[(mblk*2+wm)][frag F][lane][8], F = ((iblk*3+kk)*2+ks)*4+mi.
// A wave loads frag F with one global_load_dwordx4 at base + F*1024 + lane*16.
// ---------------------------------------------------------------------------
__global__ void repack_w2(const float* __restrict__ Wq,
                          const float* __restrict__ Wk,
                          const float* __restrict__ Wv,
                          __half* __restrict__ Wrp2) {
    int id = blockIdx.x * 256 + threadIdx.x;       // 294,912 units of 8 halves
    int mb2  = id / 12288;                         // mblk*2+wm  (0..23)
    int rem  = id % 12288;
    int F    = rem >> 6;                           // 0..191
    int lane = rem & 63;
    int mblk = mb2 >> 1, wm = mb2 & 1;
    int mi = F & 3, ks = (F >> 2) & 1, t3 = F >> 3;
    int kk = t3 % 3, iblk = t3 / 3;
    int mat = mblk >> 2;
    const float* W = (mat == 0) ? Wq : (mat == 1) ? Wk : Wv;
    int ol = ((mblk & 3) << 7) + wm * 64 + mi * 16 + (lane & 15);  // A row (m)
    int ib = iblk * 64 + ks * 32 + (lane >> 4) * 8;                // A col (k)
    half8 hv;
#pragma unroll
    for (int j = 0; j < 8; ++j)
        hv[j] = (_Float16)W[(ol * 512 + ib + j) * 3 + kk];
    *(half8*)(Wrp2 + (size_t)id * 8) = hv;
}

// Kernel 1b: transpose Wo (O,I) -> WoT (I,O) for coalesced out_kernel reads
__global__ void wot_repack(const float* __restrict__ Wo, float* __restrict__ WoT) {
    int id = blockIdx.x * 256 + threadIdx.x;       // 262,144
    int o = id & 511, i = id >> 9;
    WoT[(size_t)i * 512 + o] = Wo[(size_t)o * 512 + i];
}

// ---------------------------------------------------------------------------
// Kernel 2: fused conv1d(K=3) GEMM — NO LDS, NO BARRIERS.
// r4 lesson: barrier-locked waves stall on L2 latency simultaneously; per-wave
// MFMA duty was ~15% regardless of tile size. The B tile is only ~8 KB unique
// per wave per iblk and L2/L1-resident (Common-mistake #7: don't stage what
// caches fit), so read B fragments DIRECTLY from global:
//   bfr[ni][lane] = t16[bb][l0-1+wn*64+ni*16+lane15+kk][i0+ks*32+kgrp*8 ..+8]
// (16 rows x 4 adjacent 64B segments per load; heavy L1 reuse across kk/ks).
// With no __syncthreads, waves drift apart and hide each other's L2 latency.
// Geometry: r2's proven 128m x 128n block, 4 waves (2wm x 2wn), 64x64/wave,
// acc[4][4]=64 regs. No LDS + lean addressing -> ~115 regs; (256,4) budget
// is 128 (r1 evidence: budget = 512/N incl. acc) -> 4 waves/SIMD.
// Edge tiles (l0==0 / l0==1920) take a block-uniform predicated path.
// ---------------------------------------------------------------------------
__global__ void __launch_bounds__(256, 4) conv_gemm(
    const __half* __restrict__ t16,   // fp16 (B,L,U)
    const __half* __restrict__ Wrp2,
    const float* __restrict__ bq,
    const float* __restrict__ bk,
    const float* __restrict__ bv,
    __half* __restrict__ kbuf, __half* __restrict__ vbuf,
    unsigned* __restrict__ qmaxU, unsigned* __restrict__ kmaxU,
    unsigned* __restrict__ vmaxU) {
    const int tid  = threadIdx.x;
    const int lane = tid & 63;
    const int w    = tid >> 6;
    const int wm = w >> 1, wn = w & 1;
    // XCD swizzle: same-ntile's 12 mblk blocks land consecutively on ONE XCD.
    const int xcd  = blockIdx.x & 7;
    const int slot = blockIdx.x >> 3;          // 0..767
    const int ntile = xcd + 8 * (slot / 12);   // 0..511
    const int mblk  = slot % 12;
    const int bb = ntile >> 4;
    const int l0 = (ntile & 15) << 7;
    const int lane15 = lane & 15, kgrp = lane >> 4;

    const char* Abase = (const char*)Wrp2 + (size_t)(mblk * 2 + wm) * 196608;
    const __half* tB = t16 + (size_t)bb * L_ * U_;

    f32x4 acc[4][4];
#pragma unroll
    for (int a = 0; a < 4; ++a)
#pragma unroll
        for (int c = 0; c < 4; ++c) acc[a][c] = (f32x4){0.f, 0.f, 0.f, 0.f};

    // base sequence row for this lane's B fragments (row 0 <-> l = l0-1)
    const int base_l = l0 - 1 + wn * 64 + lane15;

    auto mainloop = [&](auto EDGE_) {
        constexpr bool EDGE = decltype(EDGE_)::value;
        for (int iblk = 0; iblk < 8; ++iblk) {
            const int i0 = iblk << 6;
#pragma unroll
            for (int s = 0; s < 6; ++s) {
                const int kk = s >> 1, ks = s & 1;
                // ---- A fragments: 4 x global_load_dwordx4 (L2-resident) ----
                half8 af[4];
#pragma unroll
                for (int mi = 0; mi < 4; ++mi)
                    af[mi] = *(const half8*)(Abase +
                        ((((size_t)iblk * 3 + kk) * 2 + ks) * 4 + mi) * 1024 + lane * 16);
                // ---- B fragments: direct global 16B/lane ----
                half8 bfr[4];
#pragma unroll
                for (int ni = 0; ni < 4; ++ni) {
                    int l = base_l + ni * 16 + kk;
                    if (EDGE) {
                        const bool ok = (unsigned)l < (unsigned)L_;
                        int lcl = l < 0 ? 0 : (l > L_ - 1 ? L_ - 1 : l);
                        half8 v = *(const half8*)(tB + (size_t)lcl * U_ +
                                                  i0 + ks * 32 + kgrp * 8);
                        bfr[ni] = ok ? v : half8{};
                    } else {
                        bfr[ni] = *(const half8*)(tB + (size_t)l * U_ +
                                                  i0 + ks * 32 + kgrp * 8);
                    }
                }
#pragma unroll
                for (int mi = 0; mi < 4; ++mi)
#pragma unroll
                    for (int ni = 0; ni < 4; ++ni)
                        acc[mi][ni] = __builtin_amdgcn_mfma_f32_16x16x32_f16(
                            af[mi], bfr[ni], acc[mi][ni], 0, 0, 0);
            }
        }
    };
    if (l0 == 0 || l0 == (L_ - 128)) mainloop(BoolC<true>{});
    else                             mainloop(BoolC<false>{});

    // ---- epilogue ----
    const int mat = mblk >> 2;                         // 0=q 1=k 2=v
    const float* bias = (mat == 0) ? bq : (mat == 1) ? bk : bv;
    const int oBase = ((mblk & 3) << 7) + wm * 64 + kgrp * 4;
#pragma unroll
    for (int mi = 0; mi < 4; ++mi) {
#pragma unroll
        for (int r = 0; r < 4; ++r) {
            const int o = oBase + mi * 16 + r;         // channel within matrix
            const float bsv = bias[o];
            float vals[4];
            float mx = -3.0e38f;
#pragma unroll
            for (int ni = 0; ni < 4; ++ni) {
                float v = acc[mi][ni][r] + bsv;
                vals[ni] = v;
                mx = fmaxf(mx, v);
            }
#pragma unroll
            for (int d = 1; d < 16; d <<= 1) mx = fmaxf(mx, __shfl_xor(mx, d, 64));
            if (mat == 0) {
                if (lane15 == 0) atomicMax(&qmaxU[bb * U_ + o], fmap(mx));
            } else {
                __half* buf = (mat == 1) ? kbuf : vbuf;
                size_t rowbase = ((size_t)bb * U_ + o) * L_ + l0 + wn * 64;
#pragma unroll
                for (int ni = 0; ni < 4; ++ni)
                    buf[rowbase + ni * 16 + lane15] = __float2half(vals[ni]);
                unsigned* mptr = (mat == 1) ? kmaxU : vmaxU;
                if (lane15 == 0) atomicMax(&mptr[bb * U_ + o], fmap(mx));
            }
        }
    }
}

// ---------------------------------------------------------------------------
// Kernel 3: per-(b,h) attention, 1024 threads. k-pass: one aligned dword load
// + 2 shfl per thread-iter (edges scalar only at wave boundaries).
// v-pass: lb = it*128 + ch*8 -> contiguous 256B per o-group (coalesced V) and
// pl[] bank conflict cut from 16-way to 4-way.
// ---------------------------------------------------------------------------
__global__ void __launch_bounds__(1024) attn_kernel(
    const __half* __restrict__ kbuf, const __half* __restrict__ vbuf,
    const unsigned* __restrict__ qmaxU, const unsigned* __restrict__ kmaxU,
    const unsigned* __restrict__ vmaxU,
    const int* __restrict__ g_mask, const int* __restrict__ t_mask,
    float* __restrict__ attout) {
    const int bh = blockIdx.x;
    const int b = bh >> 3, h = bh & 7;
    const int tid = threadIdx.x;
    const int lane = tid & 63;
    __shared__ float qs[64], kg[64], vg[64];
    __shared__ float pl[2048];
    __shared__ float red[1024];
    if (tid < 64) {
        qs[tid] = funmap(qmaxU[b * U_ + h * 64 + tid]);
        kg[tid] = funmap(kmaxU[b * U_ + h * 64 + tid]);
        vg[tid] = funmap(vmaxU[b * U_ + h * 64 + tid]);
    }
    __syncthreads();
    const float scale = 0.044194173824159216f;   // 1/sqrt(512)

    // logits for 2048 local (pooled) keys; thread owns 2 positions
    const __half* kbase = kbuf + ((size_t)b * U_ + h * 64) * L_;
    const int l0 = tid * 2;
    float acc0 = 0.f, acc1 = 0.f;
    for (int o = 0; o < 64; ++o) {
        const __half* row = kbase + (size_t)o * L_;
        const __half2 hv = *(const __half2*)(row + l0);
        float f1 = __half2float(hv.x), f2 = __half2float(hv.y);
        float fL = __shfl_up(f2, 1, 64);
        float fR = __shfl_down(f1, 1, 64);
        if (lane == 0)  fL = (l0 == 0) ? -3.0e38f : __half2float(row[l0 - 1]);
        if (lane == 63) fR = (l0 + 2 >= L_) ? -3.0e38f : __half2float(row[l0 + 2]);
        const float qw = qs[o];
        acc0 += qw * fmaxf(fL, fmaxf(f1, f2));
        acc1 += qw * fmaxf(f1, fmaxf(f2, fR));
    }
    float lmax = -3.0e38f;
    {
        int tm0 = t_mask[b * L_ + l0], tm1 = t_mask[b * L_ + l0 + 1];
        float lg0 = (tm0 == 0) ? -INFINITY : acc0 * scale;
        float lg1 = (tm1 == 0) ? -INFINITY : acc1 * scale;
        pl[l0] = lg0; pl[l0 + 1] = lg1;
        lmax = fmaxf(lg0, lg1);
    }
    // global-key logit (redundantly on all threads; cheap)
    float ag = 0.f;
    for (int d = 0; d < 64; ++d) ag += qs[d] * kg[d];
    const int gm = g_mask[b];
    float lgg = gm ? ag * scale : -INFINITY;
    // block max
    red[tid] = lmax; __syncthreads();
    for (int s = 512; s > 0; s >>= 1) {
        if (tid < s) red[tid] = fmaxf(red[tid], red[tid + s]);
        __syncthreads();
    }
    float mx = fmaxf(red[0], lgg);
    __syncthreads();
    // exponentials + denominator
    {
        float lg0 = pl[l0], lg1 = pl[l0 + 1];
        float e0 = (lg0 <= -3.0e38f) ? 0.f : __expf(lg0 - mx);
        float e1 = (lg1 <= -3.0e38f) ? 0.f : __expf(lg1 - mx);
        pl[l0] = e0; pl[l0 + 1] = e1;
        red[tid] = e0 + e1;
    }
    __syncthreads();
    for (int s = 512; s > 0; s >>= 1) {
        if (tid < s) red[tid] += red[tid + s];
        __syncthreads();
    }
    float eg = gm ? __expf(lgg - mx) : 0.f;
    float den = red[0] + eg;
    if (!(den > 0.f)) den = 1.f;
    __syncthreads();
    // weighted sum of pooled values: thread = (o = tid/16, 16 interleaved 8-chunks)
    const int o = tid >> 4;
    const int ch = tid & 15;
    const __half* vrow = vbuf + ((size_t)b * U_ + h * 64 + o) * L_;
    float s = 0.f;
    for (int it = 0; it < 16; ++it) {
        const int lb = it * 128 + ch * 8;
        union { uint4 u; __half hh[8]; } pk;
        pk.u = *(const uint4*)(vrow + lb);
        float f[10];
#pragma unroll
        for (int j = 0; j < 8; ++j) f[j + 1] = __half2float(pk.hh[j]);
        f[0] = (lb == 0) ? -3.0e38f : __half2float(vrow[lb - 1]);
        f[9] = (lb + 8 >= L_) ? -3.0e38f : __half2float(vrow[lb + 8]);
#pragma unroll
        for (int j = 0; j < 8; ++j)
            s += pl[lb + j] * fmaxf(f[j], fmaxf(f[j + 1], f[j + 2]));
    }
    red[tid] = s; __syncthreads();
    if (ch == 0) {
        float tot = 0.f;
#pragma unroll
        for (int q2 = 0; q2 < 16; ++q2) tot += red[(o << 4) + q2];
        float val = (eg * vg[o] + tot) / den;
        val *= (float)gm;
        attout[(size_t)b * U_ + h * 64 + o] = val;
    }
}

// ---------------------------------------------------------------------------
// Kernel 4: head mix (H x H) + output projection via WoT (coalesced)
// ---------------------------------------------------------------------------
__global__ void __launch_bounds__(512) out_kernel(
    const float* __restrict__ attout,
    const float* __restrict__ Wh, const float* __restrict__ bh,
    const float* __restrict__ WoT, const float* __restrict__ bo,
    float* __restrict__ out) {
    const int b = blockIdx.x;
    const int tid = threadIdx.x;
    __shared__ float tmp[512];
    const int oh = tid >> 6, d = tid & 63;
    float s = bh[oh];
#pragma unroll
    for (int i = 0; i < 8; ++i)
        s += Wh[oh * 8 + i] * attout[b * U_ + i * 64 + d];
    tmp[oh * 64 + d] = s;          // u = h*64 + d
    __syncthreads();
    float s2 = bo[tid];
    for (int i = 0; i < 512; ++i) s2 += WoT[i * 512 + tid] * tmp[i];
    out[b * U_ + tid] = s2;
}

// ---------------------------------------------------------------------------
extern "C" void kernel_launch(void* const* d_in, const int* in_sizes, int n_in,
                              void* d_out, int out_size, void* d_ws, size_t ws_size,
                              hipStream_t stream) {
    const float* t  = (const float*)d_in[0];
    // d_in[1] = g : unused by the reference
    const int* g_mask = (const int*)d_in[2];
    const int* t_mask = (const int*)d_in[3];
    const float* Wq = (const float*)d_in[4];
    const float* bq = (const float*)d_in[5];
    const float* Wk = (const float*)d_in[6];
    const float* bk = (const float*)d_in[7];
    const float* Wv = (const float*)d_in[8];
    const float* bv = (const float*)d_in[9];
    const float* Wh = (const float*)d_in[10];
    const float* bh = (const float*)d_in[11];
    const float* Wo = (const float*)d_in[12];
    const float* bo = (const float*)d_in[13];

    char* ws = (char*)d_ws;
    __half* Wrp2 = (__half*)ws;                                      // 4,718,592 B
    float* WoT   = (float*)(ws + 4718592);                           // 1,048,576 B
    __half* t16  = (__half*)(ws + 5767168);                          // 67,108,864 B
    __half* kbuf = (__half*)(ws + 5767168 + 67108864);               // 67,108,864 B
    __half* vbuf = (__half*)(ws + 5767168 + 2 * 67108864);           // 67,108,864 B
    unsigned* qmaxU = (unsigned*)(ws + 5767168 + 3 * 67108864);
    unsigned* kmaxU = qmaxU + 16384;
    unsigned* vmaxU = kmaxU + 16384;
    float* attout = (float*)(vmaxU + 16384);

    (void)hipMemsetAsync(qmaxU, 0, 3 * 16384 * sizeof(unsigned), stream);
    t_cvt<<<16384, 256, 0, stream>>>(t, t16);
    repack_w2<<<1152, 256, 0, stream>>>(Wq, Wk, Wv, Wrp2);
    wot_repack<<<1024, 256, 0, stream>>>(Wo, WoT);
    conv_gemm<<<6144, 256, 0, stream>>>(t16, Wrp2, bq, bk, bv, kbuf, vbuf,
                                        qmaxU, kmaxU, vmaxU);
    attn_kernel<<<256, 1024, 0, stream>>>(kbuf, vbuf, qmaxU, kmaxU, vmaxU,
                                          g_mask, t_mask, attout);
    out_kernel<<<32, 512, 0, stream>>>(attout, Wh, bh, WoT, bo, (float*)d_out);
}

// Round 7
// 607.274 us; speedup vs baseline: 1.9803x; 1.9803x over previous
//
#include <hip/hip_runtime.h>
#include <hip/hip_fp16.h>

#define B_  32
#define L_  2048
#define U_  512
#define H_  8
#define HD_ 64

typedef __attribute__((ext_vector_type(8))) _Float16 half8;
typedef __attribute__((ext_vector_type(4))) float f32x4;

// monotonic float->uint map for atomic max (works for negatives)
__device__ __forceinline__ unsigned fmap(float x) {
    unsigned u = __float_as_uint(x);
    return (u & 0x80000000u) ? ~u : (u | 0x80000000u);
}
__device__ __forceinline__ float funmap(unsigned m) {
    unsigned bits = (m & 0x80000000u) ? (m ^ 0x80000000u) : ~m;
    return __uint_as_float(bits);
}

// ---------------------------------------------------------------------------
// Kernel 0: t (B,L,U) fp32 -> fp16 (RTZ, hoisted from the GEMM inner loop).
// ---------------------------------------------------------------------------
__global__ void __launch_bounds__(256) t_cvt(const float* __restrict__ t,
                                             __half* __restrict__ t16) {
    const size_t id = (size_t)blockIdx.x * 256 + threadIdx.x;  // x8 floats
    const float4 a = *(const float4*)(t + id * 8);
    const float4 b = *(const float4*)(t + id * 8 + 4);
    auto p0 = __builtin_amdgcn_cvt_pkrtz(a.x, a.y);
    auto p1 = __builtin_amdgcn_cvt_pkrtz(a.z, a.w);
    auto p2 = __builtin_amdgcn_cvt_pkrtz(b.x, b.y);
    auto p3 = __builtin_amdgcn_cvt_pkrtz(b.z, b.w);
    half8 hv;
    hv[0] = p0[0]; hv[1] = p0[1]; hv[2] = p1[0]; hv[3] = p1[1];
    hv[4] = p2[0]; hv[5] = p2[1]; hv[6] = p3[0]; hv[7] = p3[1];
    *(half8*)(t16 + id * 8) = hv;
}

// ---------------------------------------------------------------------------
// Kernel 1a: repack [Wq;Wk;Wv] (O,I,3) fp32 -> fp16 in DIRECT A-FRAGMENT order:
// Wrp2[(mblk*2+wm)][frag F][lane][8], F = ((iblk*3+kk)*2+ks)*4+mi.
// A wave loads frag F with one global_load_dwordx4 at base + F*1024 + lane*16.
// ---------------------------------------------------------------------------
__global__ void repack_w2(const float* __restrict__ Wq,
                          const float* __restrict__ Wk,
                          const float* __restrict__ Wv,
                          __half* __restrict__ Wrp2) {
    int id = blockIdx.x * 256 + threadIdx.x;       // 294,912 units of 8 halves
    int mb2  = id / 12288;                         // mblk*2+wm  (0..23)
    int rem  = id % 12288;
    int F    = rem >> 6;                           // 0..191
    int lane = rem & 63;
    int mblk = mb2 >> 1, wm = mb2 & 1;
    int mi = F & 3, ks = (F >> 2) & 1, t3 = F >> 3;
    int kk = t3 % 3, iblk = t3 / 3;
    int mat = mblk >> 2;
    const float* W = (mat == 0) ? Wq : (mat == 1) ? Wk : Wv;
    int ol = ((mblk & 3) << 7) + wm * 64 + mi * 16 + (lane & 15);  // A row (m)
    int ib = iblk * 64 + ks * 32 + (lane >> 4) * 8;                // A col (k)
    half8 hv;
#pragma unroll
    for (int j = 0; j < 8; ++j)
        hv[j] = (_Float16)W[(ol * 512 + ib + j) * 3 + kk];
    *(half8*)(Wrp2 + (size_t)id * 8) = hv;
}

// Kernel 1b: transpose Wo (O,I) -> WoT (I,O) for coalesced out_kernel reads
__global__ void wot_repack(const float* __restrict__ Wo, float* __restrict__ WoT) {
    int id = blockIdx.x * 256 + threadIdx.x;       // 262,144
    int o = id & 511, i = id >> 9;
    WoT[(size_t)i * 512 + o] = Wo[(size_t)o * 512 + i];
}

// ---------------------------------------------------------------------------
// Kernel 2: fused conv1d(K=3) GEMM — r2 version VERBATIM (proven 356 µs,
// MfmaUtil 39, zero spill). r3 pipeline / r4 big-tile / r5 no-LDS all lost.
// ---------------------------------------------------------------------------
__global__ void __launch_bounds__(256, 3) conv_gemm(
    const __half* __restrict__ t16,   // fp16 (B,L,U)
    const __half* __restrict__ Wrp2,
    const float* __restrict__ bq,
    const float* __restrict__ bk,
    const float* __restrict__ bv,
    __half* __restrict__ kbuf, __half* __restrict__ vbuf,
    unsigned* __restrict__ qmaxU, unsigned* __restrict__ kmaxU,
    unsigned* __restrict__ vmaxU) {
    __shared__ __align__(16) __half lB16[2][130 * 64];   // 33,280 B total

    const int tid  = threadIdx.x;
    const int lane = tid & 63;
    const int w    = tid >> 6;
    const int wm = w >> 1, wn = w & 1;
    // XCD swizzle: same-ntile's 12 mblk blocks land consecutively on ONE XCD.
    const int xcd  = blockIdx.x & 7;
    const int slot = blockIdx.x >> 3;          // 0..767
    const int ntile = xcd + 8 * (slot / 12);   // 0..511
    const int mblk  = slot % 12;
    const int bb = ntile >> 4;
    const int l0 = (ntile & 15) << 7;
    const int lane15 = lane & 15, kgrp = lane >> 4;

    const char* Abase = (const char*)Wrp2 + (size_t)(mblk * 2 + wm) * 196608;
    const __half* tB = t16 + (size_t)bb * L_ * U_;

    f32x4 acc[4][4];
#pragma unroll
    for (int a = 0; a < 4; ++a)
#pragma unroll
        for (int c = 0; c < 4; ++c) acc[a][c] = (f32x4){0.f, 0.f, 0.f, 0.f};

    // ---- B-stage: async DMA of 130 rows x 128B, swizzled source ----
    auto stageB = [&](int nb, int buf) {
        const int i0 = nb << 6;
#pragma unroll
        for (int d = 0; d < 4; ++d) {
            const int rowb = w * 32 + d * 8;               // wave-uniform
            const int row  = rowb + (lane >> 3);
            const int l    = l0 - 1 + row;
            const int p8   = lane & 7;
            const char* g = (const char*)(tB + (size_t)l * U_ + i0) + ((p8 ^ (l & 7)) << 4);
            if (l >= 0 && l < L_)
                __builtin_amdgcn_global_load_lds(
                    (const __attribute__((address_space(1))) unsigned int*)g,
                    (__attribute__((address_space(3))) unsigned int*)((char*)lB16[buf] + rowb * 128),
                    16, 0, 0);
        }
        if (w == 0 && lane < 16) {                         // rows 128,129
            const int row = 128 + (lane >> 3);
            const int l   = l0 - 1 + row;
            const int p8  = lane & 7;
            const char* g = (const char*)(tB + (size_t)l * U_ + i0) + ((p8 ^ (l & 7)) << 4);
            if (l >= 0 && l < L_)
                __builtin_amdgcn_global_load_lds(
                    (const __attribute__((address_space(1))) unsigned int*)g,
                    (__attribute__((address_space(3))) unsigned int*)((char*)lB16[buf] + 128 * 128),
                    16, 0, 0);
        }
    };

    // prezero the (at most one) conv-padding row in both buffers
    if (l0 == 0 && tid < 64) {
        lB16[0][tid] = (__half)0.f; lB16[1][tid] = (__half)0.f;
    }
    if (l0 == 1920 && tid < 64) {
        lB16[0][129 * 64 + tid] = (__half)0.f; lB16[1][129 * 64 + tid] = (__half)0.f;
    }

    stageB(0, 0);
    __syncthreads();

    for (int iblk = 0; iblk < 8; ++iblk) {
        const int cur = iblk & 1;
        const char* bbase = (const char*)lB16[cur];
#pragma unroll
        for (int kk = 0; kk < 3; ++kk) {
#pragma unroll
            for (int ks = 0; ks < 2; ++ks) {
                // ---- A fragments for THIS (kk,ks): 4 half8 = 16 VGPRs live ----
                half8 af[4];
#pragma unroll
                for (int mi = 0; mi < 4; ++mi)
                    af[mi] = *(const half8*)(Abase +
                        ((((size_t)iblk * 3 + kk) * 2 + ks) * 4 + mi) * 1024 + lane * 16);
                // prefetch next B tile early in the iteration
                if (kk == 0 && ks == 0 && iblk < 7) stageB(iblk + 1, cur ^ 1);
                half8 bfr[4];
#pragma unroll
                for (int ni = 0; ni < 4; ++ni) {
                    const int rbuf = wn * 64 + ni * 16 + lane15 + kk;
                    const int key  = (rbuf + 7) & 7;       // = (lane15+kk+7)&7
                    const int p    = ks * 4 + kgrp;        // 16B piece 0..7
                    bfr[ni] = *(const half8*)(bbase + rbuf * 128 + ((p ^ key) << 4));
                }
#pragma unroll
                for (int mi = 0; mi < 4; ++mi)
#pragma unroll
                    for (int ni = 0; ni < 4; ++ni)
                        acc[mi][ni] = __builtin_amdgcn_mfma_f32_16x16x32_f16(
                            af[mi], bfr[ni], acc[mi][ni], 0, 0, 0);
            }
        }
        __syncthreads();
    }

    // ---- epilogue ----
    const int mat = mblk >> 2;                         // 0=q 1=k 2=v
    const float* bias = (mat == 0) ? bq : (mat == 1) ? bk : bv;
    const int oBase = ((mblk & 3) << 7) + wm * 64 + kgrp * 4;
#pragma unroll
    for (int mi = 0; mi < 4; ++mi) {
#pragma unroll
        for (int r = 0; r < 4; ++r) {
            const int o = oBase + mi * 16 + r;         // channel within matrix
            const float bsv = bias[o];
            float vals[4];
            float mx = -3.0e38f;
#pragma unroll
            for (int ni = 0; ni < 4; ++ni) {
                float v = acc[mi][ni][r] + bsv;
                vals[ni] = v;
                mx = fmaxf(mx, v);
            }
#pragma unroll
            for (int d = 1; d < 16; d <<= 1) mx = fmaxf(mx, __shfl_xor(mx, d, 64));
            if (mat == 0) {
                if (lane15 == 0) atomicMax(&qmaxU[bb * U_ + o], fmap(mx));
            } else {
                __half* buf = (mat == 1) ? kbuf : vbuf;
                size_t rowbase = ((size_t)bb * U_ + o) * L_ + l0 + wn * 64;
#pragma unroll
                for (int ni = 0; ni < 4; ++ni)
                    buf[rowbase + ni * 16 + lane15] = __float2half(vals[ni]);
                unsigned* mptr = (mat == 1) ? kmaxU : vmaxU;
                if (lane15 == 0) atomicMax(&mptr[bb * U_ + o], fmap(mx));
            }
        }
    }
}

// ---------------------------------------------------------------------------
// Kernel 3: per-(b,h) attention, 1024 threads — latency-optimized rewrite.
//  k-pass: 3 overlapping __half2 loads per (o,thread) (l0-2, l0, l0+2),
//    clamped base offsets hoisted; edge fix via constant-per-thread selects.
//    NO shfl, NO divergent branches in the loop -> unrollable, 12 loads in
//    flight. (Old version: 2 dependent shfls + 2 divergent scalar loads per
//    iteration blocked ILP.)
//  reductions: wave shfl_xor + 16-slot LDS; 3 __syncthreads total (was ~25).
//  v-pass: r3 coalesced layout; final 16-way sum via intra-wave shfl_xor.
// ---------------------------------------------------------------------------
__global__ void __launch_bounds__(1024) attn_kernel(
    const __half* __restrict__ kbuf, const __half* __restrict__ vbuf,
    const unsigned* __restrict__ qmaxU, const unsigned* __restrict__ kmaxU,
    const unsigned* __restrict__ vmaxU,
    const int* __restrict__ g_mask, const int* __restrict__ t_mask,
    float* __restrict__ attout) {
    const int bh = blockIdx.x;
    const int b = bh >> 3, h = bh & 7;
    const int tid = threadIdx.x;
    const int lane = tid & 63;
    const int wid = tid >> 6;
    __shared__ float qs[64], kg[64], vg[64];
    __shared__ float pl[2048];
    __shared__ float wredA[16], wredB[16];
    if (tid < 64) {
        qs[tid] = funmap(qmaxU[b * U_ + h * 64 + tid]);
        kg[tid] = funmap(kmaxU[b * U_ + h * 64 + tid]);
        vg[tid] = funmap(vmaxU[b * U_ + h * 64 + tid]);
    }
    __syncthreads();
    const float scale = 0.044194173824159216f;   // 1/sqrt(512)

    // ---- k-pass: logits for 2048 pooled keys, thread owns l0, l0+1 ----
    const __half* kbase = kbuf + ((size_t)b * U_ + h * 64) * L_;
    const int l0 = tid * 2;
    const int offm = (l0 == 0) ? 0 : l0 - 2;          // clamped, fix below
    const int offp = (l0 + 2 >= L_) ? L_ - 2 : l0 + 2;
    const bool mE = (l0 == 0), pE = (l0 + 2 >= L_);
    float acc0 = 0.f, acc1 = 0.f;
    {
        const __half* pr = kbase;
#pragma unroll 4
        for (int o = 0; o < 64; ++o) {
            const __half2 hm = *(const __half2*)(pr + offm);
            const __half2 hc = *(const __half2*)(pr + l0);
            const __half2 hp = *(const __half2*)(pr + offp);
            const float fL = mE ? -3.0e38f : __half2float(hm.y);   // k[l0-1]
            const float f1 = __half2float(hc.x), f2 = __half2float(hc.y);
            const float fR = pE ? -3.0e38f : __half2float(hp.x);   // k[l0+2]
            const float qw = qs[o];
            acc0 += qw * fmaxf(fL, fmaxf(f1, f2));
            acc1 += qw * fmaxf(f1, fmaxf(f2, fR));
            pr += L_;
        }
    }
    float lg0, lg1;
    {
        const int tm0 = t_mask[b * L_ + l0], tm1 = t_mask[b * L_ + l0 + 1];
        lg0 = (tm0 == 0) ? -INFINITY : acc0 * scale;
        lg1 = (tm1 == 0) ? -INFINITY : acc1 * scale;
    }
    // ---- block max: wave shfl reduce + 16 LDS slots + 1 barrier ----
    float lmax = fmaxf(lg0, lg1);
#pragma unroll
    for (int d = 1; d < 64; d <<= 1) lmax = fmaxf(lmax, __shfl_xor(lmax, d, 64));
    if (lane == 0) wredA[wid] = lmax;
    // global-key logit (redundantly on all threads; cheap, overlaps barrier)
    float ag = 0.f;
#pragma unroll 8
    for (int d = 0; d < 64; ++d) ag += qs[d] * kg[d];
    const int gm = g_mask[b];
    const float lgg = gm ? ag * scale : -INFINITY;
    __syncthreads();
    float mx = lgg;
#pragma unroll
    for (int i = 0; i < 16; ++i) mx = fmaxf(mx, wredA[i]);
    // ---- exp + denominator ----
    const float e0 = (lg0 <= -3.0e38f) ? 0.f : __expf(lg0 - mx);
    const float e1 = (lg1 <= -3.0e38f) ? 0.f : __expf(lg1 - mx);
    pl[l0] = e0; pl[l0 + 1] = e1;
    float psum = e0 + e1;
#pragma unroll
    for (int d = 1; d < 64; d <<= 1) psum += __shfl_xor(psum, d, 64);
    if (lane == 0) wredB[wid] = psum;
    __syncthreads();                       // also publishes pl[] for v-pass
    const float eg = gm ? __expf(lgg - mx) : 0.f;
    float den = eg;
#pragma unroll
    for (int i = 0; i < 16; ++i) den += wredB[i];
    if (!(den > 0.f)) den = 1.f;
    // ---- v-pass: thread = (o = tid/16, 16 interleaved 8-chunks) ----
    const int o = tid >> 4;
    const int ch = tid & 15;
    const __half* vrow = vbuf + ((size_t)b * U_ + h * 64 + o) * L_;
    float s = 0.f;
#pragma unroll 2
    for (int it = 0; it < 16; ++it) {
        const int lb = it * 128 + ch * 8;
        union { uint4 u; __half hh[8]; } pk;
        pk.u = *(const uint4*)(vrow + lb);
        float f[10];
#pragma unroll
        for (int j = 0; j < 8; ++j) f[j + 1] = __half2float(pk.hh[j]);
        f[0] = (lb == 0) ? -3.0e38f : __half2float(vrow[lb - 1]);
        f[9] = (lb + 8 >= L_) ? -3.0e38f : __half2float(vrow[lb + 8]);
#pragma unroll
        for (int j = 0; j < 8; ++j)
            s += pl[lb + j] * fmaxf(f[j], fmaxf(f[j + 1], f[j + 2]));
    }
    // 16 ch's of an o are contiguous lanes: reduce via shfl_xor, no barrier
#pragma unroll
    for (int d = 1; d < 16; d <<= 1) s += __shfl_xor(s, d, 64);
    if (ch == 0) {
        float val = (eg * vg[o] + s) / den;
        val *= (float)gm;
        attout[(size_t)b * U_ + h * 64 + o] = val;
    }
}

// ---------------------------------------------------------------------------
// Kernel 4: head mix (H x H) + output projection via WoT (coalesced)
// ---------------------------------------------------------------------------
__global__ void __launch_bounds__(512) out_kernel(
    const float* __restrict__ attout,
    const float* __restrict__ Wh, const float* __restrict__ bh,
    const float* __restrict__ WoT, const float* __restrict__ bo,
    float* __restrict__ out) {
    const int b = blockIdx.x;
    const int tid = threadIdx.x;
    __shared__ float tmp[512];
    const int oh = tid >> 6, d = tid & 63;
    float s = bh[oh];
#pragma unroll
    for (int i = 0; i < 8; ++i)
        s += Wh[oh * 8 + i] * attout[b * U_ + i * 64 + d];
    tmp[oh * 64 + d] = s;          // u = h*64 + d
    __syncthreads();
    float s2 = bo[tid];
    for (int i = 0; i < 512; ++i) s2 += WoT[i * 512 + tid] * tmp[i];
    out[b * U_ + tid] = s2;
}

// ---------------------------------------------------------------------------
extern "C" void kernel_launch(void* const* d_in, const int* in_sizes, int n_in,
                              void* d_out, int out_size, void* d_ws, size_t ws_size,
                              hipStream_t stream) {
    const float* t  = (const float*)d_in[0];
    // d_in[1] = g : unused by the reference
    const int* g_mask = (const int*)d_in[2];
    const int* t_mask = (const int*)d_in[3];
    const float* Wq = (const float*)d_in[4];
    const float* bq = (const float*)d_in[5];
    const float* Wk = (const float*)d_in[6];
    const float* bk = (const float*)d_in[7];
    const float* Wv = (const float*)d_in[8];
    const float* bv = (const float*)d_in[9];
    const float* Wh = (const float*)d_in[10];
    const float* bh = (const float*)d_in[11];
    const float* Wo = (const float*)d_in[12];
    const float* bo = (const float*)d_in[13];

    char* ws = (char*)d_ws;
    __half* Wrp2 = (__half*)ws;                                      // 4,718,592 B
    float* WoT   = (float*)(ws + 4718592);                           // 1,048,576 B
    __half* t16  = (__half*)(ws + 5767168);                          // 67,108,864 B
    __half* kbuf = (__half*)(ws + 5767168 + 67108864);               // 67,108,864 B
    __half* vbuf = (__half*)(ws + 5767168 + 2 * 67108864);           // 67,108,864 B
    unsigned* qmaxU = (unsigned*)(ws + 5767168 + 3 * 67108864);
    unsigned* kmaxU = qmaxU + 16384;
    unsigned* vmaxU = kmaxU + 16384;
    float* attout = (float*)(vmaxU + 16384);

    (void)hipMemsetAsync(qmaxU, 0, 3 * 16384 * sizeof(unsigned), stream);
    t_cvt<<<16384, 256, 0, stream>>>(t, t16);
    repack_w2<<<1152, 256, 0, stream>>>(Wq, Wk, Wv, Wrp2);
    wot_repack<<<1024, 256, 0, stream>>>(Wo, WoT);
    conv_gemm<<<6144, 256, 0, stream>>>(t16, Wrp2, bq, bk, bv, kbuf, vbuf,
                                        qmaxU, kmaxU, vmaxU);
    attn_kernel<<<256, 1024, 0, stream>>>(kbuf, vbuf, qmaxU, kmaxU, vmaxU,
                                          g_mask, t_mask, attout);
    out_kernel<<<32, 512, 0, stream>>>(attout, Wh, bh, WoT, bo, (float*)d_out);
}

// Round 8
// 594.044 us; speedup vs baseline: 2.0244x; 1.0223x over previous
//
#include <hip/hip_runtime.h>
#include <hip/hip_fp16.h>

#define B_  32
#define L_  2048
#define U_  512
#define H_  8
#define HD_ 64

typedef __attribute__((ext_vector_type(8))) _Float16 half8;
typedef __attribute__((ext_vector_type(4))) float f32x4;

// monotonic float->uint map for atomic max (works for negatives)
__device__ __forceinline__ unsigned fmap(float x) {
    unsigned u = __float_as_uint(x);
    return (u & 0x80000000u) ? ~u : (u | 0x80000000u);
}
__device__ __forceinline__ float funmap(unsigned m) {
    unsigned bits = (m & 0x80000000u) ? (m ^ 0x80000000u) : ~m;
    return __uint_as_float(bits);
}

// ---------------------------------------------------------------------------
// Kernel 0: t (B,L,U) fp32 -> fp16 (RTZ, hoisted from the GEMM inner loop).
// ---------------------------------------------------------------------------
__global__ void __launch_bounds__(256) t_cvt(const float* __restrict__ t,
                                             __half* __restrict__ t16) {
    const size_t id = (size_t)blockIdx.x * 256 + threadIdx.x;  // x8 floats
    const float4 a = *(const float4*)(t + id * 8);
    const float4 b = *(const float4*)(t + id * 8 + 4);
    auto p0 = __builtin_amdgcn_cvt_pkrtz(a.x, a.y);
    auto p1 = __builtin_amdgcn_cvt_pkrtz(a.z, a.w);
    auto p2 = __builtin_amdgcn_cvt_pkrtz(b.x, b.y);
    auto p3 = __builtin_amdgcn_cvt_pkrtz(b.z, b.w);
    half8 hv;
    hv[0] = p0[0]; hv[1] = p0[1]; hv[2] = p1[0]; hv[3] = p1[1];
    hv[4] = p2[0]; hv[5] = p2[1]; hv[6] = p3[0]; hv[7] = p3[1];
    *(half8*)(t16 + id * 8) = hv;
}

// ---------------------------------------------------------------------------
// Kernel 1a: repack [Wq;Wk;Wv] (O,I,3) fp32 -> fp16 in DIRECT A-FRAGMENT order:
// Wrp2[(mblk*2+wm)][frag F][lane][8], F = ((iblk*3+kk)*2+ks)*4+mi.
// A wave loads frag F with one global_load_dwordx4 at base + F*1024 + lane*16.
// ---------------------------------------------------------------------------
__global__ void repack_w2(const float* __restrict__ Wq,
                          const float* __restrict__ Wk,
                          const float* __restrict__ Wv,
                          __half* __restrict__ Wrp2) {
    int id = blockIdx.x * 256 + threadIdx.x;       // 294,912 units of 8 halves
    int mb2  = id / 12288;                         // mblk*2+wm  (0..23)
    int rem  = id % 12288;
    int F    = rem >> 6;                           // 0..191
    int lane = rem & 63;
    int mblk = mb2 >> 1, wm = mb2 & 1;
    int mi = F & 3, ks = (F >> 2) & 1, t3 = F >> 3;
    int kk = t3 % 3, iblk = t3 / 3;
    int mat = mblk >> 2;
    const float* W = (mat == 0) ? Wq : (mat == 1) ? Wk : Wv;
    int ol = ((mblk & 3) << 7) + wm * 64 + mi * 16 + (lane & 15);  // A row (m)
    int ib = iblk * 64 + ks * 32 + (lane >> 4) * 8;                // A col (k)
    half8 hv;
#pragma unroll
    for (int j = 0; j < 8; ++j)
        hv[j] = (_Float16)W[(ol * 512 + ib + j) * 3 + kk];
    *(half8*)(Wrp2 + (size_t)id * 8) = hv;
}

// Kernel 1b: transpose Wo (O,I) -> WoT (I,O) for coalesced out_kernel reads
__global__ void wot_repack(const float* __restrict__ Wo, float* __restrict__ WoT) {
    int id = blockIdx.x * 256 + threadIdx.x;       // 262,144
    int o = id & 511, i = id >> 9;
    WoT[(size_t)i * 512 + o] = Wo[(size_t)o * 512 + i];
}

// ---------------------------------------------------------------------------
// Kernel 2: fused conv1d(K=3) GEMM — r2 loop body VERBATIM (proven 356 µs,
// zero spill). ONLY change vs r7: mblk-GROUPED XCD swizzle. Old order cycled
// all 12 A panels (4.7 MB) per XCD against a 4 MB L2 -> A thrashed to L3
// (FETCH showed ~150 MB of A re-fetch; A-frag loads paid L3 latency in every
// subphase). New order: each XCD runs {6 mblk} x {its 64 ntiles} for group 0,
// then group 1 -> per-XCD A working set 2.3 MB (L2-resident), B re-streamed
// 2x (cheap: +64 MB sequential).
// ---------------------------------------------------------------------------
__global__ void __launch_bounds__(256, 3) conv_gemm(
    const __half* __restrict__ t16,   // fp16 (B,L,U)
    const __half* __restrict__ Wrp2,
    const float* __restrict__ bq,
    const float* __restrict__ bk,
    const float* __restrict__ bv,
    __half* __restrict__ kbuf, __half* __restrict__ vbuf,
    unsigned* __restrict__ qmaxU, unsigned* __restrict__ kmaxU,
    unsigned* __restrict__ vmaxU) {
    __shared__ __align__(16) __half lB16[2][130 * 64];   // 33,280 B total

    const int tid  = threadIdx.x;
    const int lane = tid & 63;
    const int w    = tid >> 6;
    const int wm = w >> 1, wn = w & 1;
    // mblk-grouped XCD swizzle: blockIdx = ((g*64+chunk)*6 + m6)*8 + xcd
    const int xcd  = blockIdx.x & 7;
    const int slot = blockIdx.x >> 3;          // 0..767
    const int g    = slot / 384;               // A-panel group 0..1
    const int r    = slot % 384;
    const int chunk= r / 6;                    // 0..63
    const int mblk = g * 6 + (r % 6);          // 0..11
    const int ntile= xcd + 8 * chunk;          // 0..511
    const int bb = ntile >> 4;
    const int l0 = (ntile & 15) << 7;
    const int lane15 = lane & 15, kgrp = lane >> 4;

    const char* Abase = (const char*)Wrp2 + (size_t)(mblk * 2 + wm) * 196608;
    const __half* tB = t16 + (size_t)bb * L_ * U_;

    f32x4 acc[4][4];
#pragma unroll
    for (int a = 0; a < 4; ++a)
#pragma unroll
        for (int c = 0; c < 4; ++c) acc[a][c] = (f32x4){0.f, 0.f, 0.f, 0.f};

    // ---- B-stage: async DMA of 130 rows x 128B, swizzled source ----
    auto stageB = [&](int nb, int buf) {
        const int i0 = nb << 6;
#pragma unroll
        for (int d = 0; d < 4; ++d) {
            const int rowb = w * 32 + d * 8;               // wave-uniform
            const int row  = rowb + (lane >> 3);
            const int l    = l0 - 1 + row;
            const int p8   = lane & 7;
            const char* g2 = (const char*)(tB + (size_t)l * U_ + i0) + ((p8 ^ (l & 7)) << 4);
            if (l >= 0 && l < L_)
                __builtin_amdgcn_global_load_lds(
                    (const __attribute__((address_space(1))) unsigned int*)g2,
                    (__attribute__((address_space(3))) unsigned int*)((char*)lB16[buf] + rowb * 128),
                    16, 0, 0);
        }
        if (w == 0 && lane < 16) {                         // rows 128,129
            const int row = 128 + (lane >> 3);
            const int l   = l0 - 1 + row;
            const int p8  = lane & 7;
            const char* g2 = (const char*)(tB + (size_t)l * U_ + i0) + ((p8 ^ (l & 7)) << 4);
            if (l >= 0 && l < L_)
                __builtin_amdgcn_global_load_lds(
                    (const __attribute__((address_space(1))) unsigned int*)g2,
                    (__attribute__((address_space(3))) unsigned int*)((char*)lB16[buf] + 128 * 128),
                    16, 0, 0);
        }
    };

    // prezero the (at most one) conv-padding row in both buffers
    if (l0 == 0 && tid < 64) {
        lB16[0][tid] = (__half)0.f; lB16[1][tid] = (__half)0.f;
    }
    if (l0 == 1920 && tid < 64) {
        lB16[0][129 * 64 + tid] = (__half)0.f; lB16[1][129 * 64 + tid] = (__half)0.f;
    }

    stageB(0, 0);
    __syncthreads();

    for (int iblk = 0; iblk < 8; ++iblk) {
        const int cur = iblk & 1;
        const char* bbase = (const char*)lB16[cur];
#pragma unroll
        for (int kk = 0; kk < 3; ++kk) {
#pragma unroll
            for (int ks = 0; ks < 2; ++ks) {
                // ---- A fragments for THIS (kk,ks): 4 half8 = 16 VGPRs live ----
                half8 af[4];
#pragma unroll
                for (int mi = 0; mi < 4; ++mi)
                    af[mi] = *(const half8*)(Abase +
                        ((((size_t)iblk * 3 + kk) * 2 + ks) * 4 + mi) * 1024 + lane * 16);
                // prefetch next B tile early in the iteration
                if (kk == 0 && ks == 0 && iblk < 7) stageB(iblk + 1, cur ^ 1);
                half8 bfr[4];
#pragma unroll
                for (int ni = 0; ni < 4; ++ni) {
                    const int rbuf = wn * 64 + ni * 16 + lane15 + kk;
                    const int key  = (rbuf + 7) & 7;       // = (lane15+kk+7)&7
                    const int p    = ks * 4 + kgrp;        // 16B piece 0..7
                    bfr[ni] = *(const half8*)(bbase + rbuf * 128 + ((p ^ key) << 4));
                }
#pragma unroll
                for (int mi = 0; mi < 4; ++mi)
#pragma unroll
                    for (int ni = 0; ni < 4; ++ni)
                        acc[mi][ni] = __builtin_amdgcn_mfma_f32_16x16x32_f16(
                            af[mi], bfr[ni], acc[mi][ni], 0, 0, 0);
            }
        }
        __syncthreads();
    }

    // ---- epilogue ----
    const int mat = mblk >> 2;                         // 0=q 1=k 2=v
    const float* bias = (mat == 0) ? bq : (mat == 1) ? bk : bv;
    const int oBase = ((mblk & 3) << 7) + wm * 64 + kgrp * 4;
#pragma unroll
    for (int mi = 0; mi < 4; ++mi) {
#pragma unroll
        for (int r2 = 0; r2 < 4; ++r2) {
            const int o = oBase + mi * 16 + r2;        // channel within matrix
            const float bsv = bias[o];
            float vals[4];
            float mx = -3.0e38f;
#pragma unroll
            for (int ni = 0; ni < 4; ++ni) {
                float v = acc[mi][ni][r2] + bsv;
                vals[ni] = v;
                mx = fmaxf(mx, v);
            }
#pragma unroll
            for (int d = 1; d < 16; d <<= 1) mx = fmaxf(mx, __shfl_xor(mx, d, 64));
            if (mat == 0) {
                if (lane15 == 0) atomicMax(&qmaxU[bb * U_ + o], fmap(mx));
            } else {
                __half* buf = (mat == 1) ? kbuf : vbuf;
                size_t rowbase = ((size_t)bb * U_ + o) * L_ + l0 + wn * 64;
#pragma unroll
                for (int ni = 0; ni < 4; ++ni)
                    buf[rowbase + ni * 16 + lane15] = __float2half(vals[ni]);
                unsigned* mptr = (mat == 1) ? kmaxU : vmaxU;
                if (lane15 == 0) atomicMax(&mptr[bb * U_ + o], fmap(mx));
            }
        }
    }
}

// ---------------------------------------------------------------------------
// Kernel 3: per-(b,h) attention, 1024 threads — r6/r7 latency-optimized form
// (proven: −44 µs vs r2-era version). Unchanged.
// ---------------------------------------------------------------------------
__global__ void __launch_bounds__(1024) attn_kernel(
    const __half* __restrict__ kbuf, const __half* __restrict__ vbuf,
    const unsigned* __restrict__ qmaxU, const unsigned* __restrict__ kmaxU,
    const unsigned* __restrict__ vmaxU,
    const int* __restrict__ g_mask, const int* __restrict__ t_mask,
    float* __restrict__ attout) {
    const int bh = blockIdx.x;
    const int b = bh >> 3, h = bh & 7;
    const int tid = threadIdx.x;
    const int lane = tid & 63;
    const int wid = tid >> 6;
    __shared__ float qs[64], kg[64], vg[64];
    __shared__ float pl[2048];
    __shared__ float wredA[16], wredB[16];
    if (tid < 64) {
        qs[tid] = funmap(qmaxU[b * U_ + h * 64 + tid]);
        kg[tid] = funmap(kmaxU[b * U_ + h * 64 + tid]);
        vg[tid] = funmap(vmaxU[b * U_ + h * 64 + tid]);
    }
    __syncthreads();
    const float scale = 0.044194173824159216f;   // 1/sqrt(512)

    // ---- k-pass: logits for 2048 pooled keys, thread owns l0, l0+1 ----
    const __half* kbase = kbuf + ((size_t)b * U_ + h * 64) * L_;
    const int l0 = tid * 2;
    const int offm = (l0 == 0) ? 0 : l0 - 2;          // clamped, fix below
    const int offp = (l0 + 2 >= L_) ? L_ - 2 : l0 + 2;
    const bool mE = (l0 == 0), pE = (l0 + 2 >= L_);
    float acc0 = 0.f, acc1 = 0.f;
    {
        const __half* pr = kbase;
#pragma unroll 4
        for (int o = 0; o < 64; ++o) {
            const __half2 hm = *(const __half2*)(pr + offm);
            const __half2 hc = *(const __half2*)(pr + l0);
            const __half2 hp = *(const __half2*)(pr + offp);
            const float fL = mE ? -3.0e38f : __half2float(hm.y);   // k[l0-1]
            const float f1 = __half2float(hc.x), f2 = __half2float(hc.y);
            const float fR = pE ? -3.0e38f : __half2float(hp.x);   // k[l0+2]
            const float qw = qs[o];
            acc0 += qw * fmaxf(fL, fmaxf(f1, f2));
            acc1 += qw * fmaxf(f1, fmaxf(f2, fR));
            pr += L_;
        }
    }
    float lg0, lg1;
    {
        const int tm0 = t_mask[b * L_ + l0], tm1 = t_mask[b * L_ + l0 + 1];
        lg0 = (tm0 == 0) ? -INFINITY : acc0 * scale;
        lg1 = (tm1 == 0) ? -INFINITY : acc1 * scale;
    }
    // ---- block max: wave shfl reduce + 16 LDS slots + 1 barrier ----
    float lmax = fmaxf(lg0, lg1);
#pragma unroll
    for (int d = 1; d < 64; d <<= 1) lmax = fmaxf(lmax, __shfl_xor(lmax, d, 64));
    if (lane == 0) wredA[wid] = lmax;
    // global-key logit (redundantly on all threads; cheap, overlaps barrier)
    float ag = 0.f;
#pragma unroll 8
    for (int d = 0; d < 64; ++d) ag += qs[d] * kg[d];
    const int gm = g_mask[b];
    const float lgg = gm ? ag * scale : -INFINITY;
    __syncthreads();
    float mx = lgg;
#pragma unroll
    for (int i = 0; i < 16; ++i) mx = fmaxf(mx, wredA[i]);
    // ---- exp + denominator ----
    const float e0 = (lg0 <= -3.0e38f) ? 0.f : __expf(lg0 - mx);
    const float e1 = (lg1 <= -3.0e38f) ? 0.f : __expf(lg1 - mx);
    pl[l0] = e0; pl[l0 + 1] = e1;
    float psum = e0 + e1;
#pragma unroll
    for (int d = 1; d < 64; d <<= 1) psum += __shfl_xor(psum, d, 64);
    if (lane == 0) wredB[wid] = psum;
    __syncthreads();                       // also publishes pl[] for v-pass
    const float eg = gm ? __expf(lgg - mx) : 0.f;
    float den = eg;
#pragma unroll
    for (int i = 0; i < 16; ++i) den += wredB[i];
    if (!(den > 0.f)) den = 1.f;
    // ---- v-pass: thread = (o = tid/16, 16 interleaved 8-chunks) ----
    const int o = tid >> 4;
    const int ch = tid & 15;
    const __half* vrow = vbuf + ((size_t)b * U_ + h * 64 + o) * L_;
    float s = 0.f;
#pragma unroll 2
    for (int it = 0; it < 16; ++it) {
        const int lb = it * 128 + ch * 8;
        union { uint4 u; __half hh[8]; } pk;
        pk.u = *(const uint4*)(vrow + lb);
        float f[10];
#pragma unroll
        for (int j = 0; j < 8; ++j) f[j + 1] = __half2float(pk.hh[j]);
        f[0] = (lb == 0) ? -3.0e38f : __half2float(vrow[lb - 1]);
        f[9] = (lb + 8 >= L_) ? -3.0e38f : __half2float(vrow[lb + 8]);
#pragma unroll
        for (int j = 0; j < 8; ++j)
            s += pl[lb + j] * fmaxf(f[j], fmaxf(f[j + 1], f[j + 2]));
    }
    // 16 ch's of an o are contiguous lanes: reduce via shfl_xor, no barrier
#pragma unroll
    for (int d = 1; d < 16; d <<= 1) s += __shfl_xor(s, d, 64);
    if (ch == 0) {
        float val = (eg * vg[o] + s) / den;
        val *= (float)gm;
        attout[(size_t)b * U_ + h * 64 + o] = val;
    }
}

// ---------------------------------------------------------------------------
// Kernel 4: head mix (H x H) + output projection via WoT (coalesced)
// ---------------------------------------------------------------------------
__global__ void __launch_bounds__(512) out_kernel(
    const float* __restrict__ attout,
    const float* __restrict__ Wh, const float* __restrict__ bh,
    const float* __restrict__ WoT, const float* __restrict__ bo,
    float* __restrict__ out) {
    const int b = blockIdx.x;
    const int tid = threadIdx.x;
    __shared__ float tmp[512];
    const int oh = tid >> 6, d = tid & 63;
    float s = bh[oh];
#pragma unroll
    for (int i = 0; i < 8; ++i)
        s += Wh[oh * 8 + i] * attout[b * U_ + i * 64 + d];
    tmp[oh * 64 + d] = s;          // u = h*64 + d
    __syncthreads();
    float s2 = bo[tid];
    for (int i = 0; i < 512; ++i) s2 += WoT[i * 512 + tid] * tmp[i];
    out[b * U_ + tid] = s2;
}

// ---------------------------------------------------------------------------
extern "C" void kernel_launch(void* const* d_in, const int* in_sizes, int n_in,
                              void* d_out, int out_size, void* d_ws, size_t ws_size,
                              hipStream_t stream) {
    const float* t  = (const float*)d_in[0];
    // d_in[1] = g : unused by the reference
    const int* g_mask = (const int*)d_in[2];
    const int* t_mask = (const int*)d_in[3];
    const float* Wq = (const float*)d_in[4];
    const float* bq = (const float*)d_in[5];
    const float* Wk = (const float*)d_in[6];
    const float* bk = (const float*)d_in[7];
    const float* Wv = (const float*)d_in[8];
    const float* bv = (const float*)d_in[9];
    const float* Wh = (const float*)d_in[10];
    const float* bh = (const float*)d_in[11];
    const float* Wo = (const float*)d_in[12];
    const float* bo = (const float*)d_in[13];

    char* ws = (char*)d_ws;
    __half* Wrp2 = (__half*)ws;                                      // 4,718,592 B
    float* WoT   = (float*)(ws + 4718592);                           // 1,048,576 B
    __half* t16  = (__half*)(ws + 5767168);                          // 67,108,864 B
    __half* kbuf = (__half*)(ws + 5767168 + 67108864);               // 67,108,864 B
    __half* vbuf = (__half*)(ws + 5767168 + 2 * 67108864);           // 67,108,864 B
    unsigned* qmaxU = (unsigned*)(ws + 5767168 + 3 * 67108864);
    unsigned* kmaxU = qmaxU + 16384;
    unsigned* vmaxU = kmaxU + 16384;
    float* attout = (float*)(vmaxU + 16384);

    (void)hipMemsetAsync(qmaxU, 0, 3 * 16384 * sizeof(unsigned), stream);
    t_cvt<<<16384, 256, 0, stream>>>(t, t16);
    repack_w2<<<1152, 256, 0, stream>>>(Wq, Wk, Wv, Wrp2);
    wot_repack<<<1024, 256, 0, stream>>>(Wo, WoT);
    conv_gemm<<<6144, 256, 0, stream>>>(t16, Wrp2, bq, bk, bv, kbuf, vbuf,
                                        qmaxU, kmaxU, vmaxU);
    attn_kernel<<<256, 1024, 0, stream>>>(kbuf, vbuf, qmaxU, kmaxU, vmaxU,
                                          g_mask, t_mask, attout);
    out_kernel<<<32, 512, 0, stream>>>(attout, Wh, bh, WoT, bo, (float*)d_out);
}